// Round 1
// baseline (284.322 us; speedup 1.0000x reference)
//
#include <hip/hip_runtime.h>

#define IMG_H 480
#define IMG_W 480
#define ATT_H 30
#define ATT_W 30
#define PAD 48
#define NCH 3
#define NB 32

// Kernel 1: per-sample theta + mask bounding box (+pad, clamped), stored as int4 per sample.
__global__ void __launch_bounds__(256) bbox_kernel(const float* __restrict__ atten,
                                                   int* __restrict__ box) {
    const int b = blockIdx.x;
    const int tid = threadIdx.x;
    __shared__ float s_att[ATT_H * ATT_W];
    __shared__ float s_red[4];
    __shared__ float s_theta;
    __shared__ int s_minr, s_maxr, s_minc, s_maxc;

    const float* a = atten + (size_t)b * ATT_H * ATT_W;
    for (int i = tid; i < ATT_H * ATT_W; i += 256) s_att[i] = a[i];
    if (tid == 0) { s_minr = IMG_H; s_maxr = -1; s_minc = IMG_W; s_maxc = -1; }
    __syncthreads();

    // block max-reduce over the 900 attention values
    float m = -1e30f;
    for (int i = tid; i < ATT_H * ATT_W; i += 256) m = fmaxf(m, s_att[i]);
    #pragma unroll
    for (int off = 32; off > 0; off >>= 1) m = fmaxf(m, __shfl_down(m, off, 64));
    if ((tid & 63) == 0) s_red[tid >> 6] = m;
    __syncthreads();
    if (tid == 0) {
        float t = fmaxf(fmaxf(s_red[0], s_red[1]), fmaxf(s_red[2], s_red[3]));
        s_theta = 0.5f * t;
    }
    __syncthreads();
    const float theta = s_theta;

    // brute-force the 480x480 upsampled mask; track bbox locally then LDS-atomic merge
    int minr = IMG_H, maxr = -1, minc = IMG_W, maxc = -1;
    for (int p = tid; p < IMG_H * IMG_W; p += 256) {
        const int y = p / IMG_W;
        const int x = p - y * IMG_W;
        // source coords: (i+0.5)*(30/480) - 0.5, clipped — scale is exactly 1/16
        float sy = (y + 0.5f) * 0.0625f - 0.5f;
        sy = fminf(fmaxf(sy, 0.0f), (float)(ATT_H - 1));
        const float fy0 = floorf(sy);
        const int r0 = (int)fy0;
        const int r1 = min(r0 + 1, ATT_H - 1);
        const float wr = sy - fy0;

        float sx = (x + 0.5f) * 0.0625f - 0.5f;
        sx = fminf(fmaxf(sx, 0.0f), (float)(ATT_W - 1));
        const float fx0 = floorf(sx);
        const int c0 = (int)fx0;
        const int c1 = min(c0 + 1, ATT_W - 1);
        const float wc = sx - fx0;

        // same op order as reference: row blend first, then column blend
        const float rb0 = s_att[r0 * ATT_W + c0] * (1.0f - wr) + s_att[r1 * ATT_W + c0] * wr;
        const float rb1 = s_att[r0 * ATT_W + c1] * (1.0f - wr) + s_att[r1 * ATT_W + c1] * wr;
        const float v = rb0 * (1.0f - wc) + rb1 * wc;
        if (v >= theta) {
            minr = min(minr, y); maxr = max(maxr, y);
            minc = min(minc, x); maxc = max(maxc, x);
        }
    }
    atomicMin(&s_minr, minr); atomicMax(&s_maxr, maxr);
    atomicMin(&s_minc, minc); atomicMax(&s_maxc, maxc);
    __syncthreads();
    if (tid == 0) {
        box[b * 4 + 0] = max(s_minr - PAD, 0);
        box[b * 4 + 1] = min(s_maxr + PAD, IMG_H);
        box[b * 4 + 2] = max(s_minc - PAD, 0);
        box[b * 4 + 3] = min(s_maxc + PAD, IMG_W);
    }
}

// Kernel 2: per-pixel crop-resize gather + mixup blend.
__global__ void __launch_bounds__(256) blend_kernel(const float* __restrict__ images,
                                                    const int* __restrict__ box,
                                                    float* __restrict__ out) {
    const int b = blockIdx.z;
    const int c = blockIdx.y;
    const int p = blockIdx.x * 256 + threadIdx.x;
    if (p >= IMG_H * IMG_W) return;
    const int y = p / IMG_W;
    const int x = p - y * IMG_W;

    const int h0 = box[b * 4 + 0];
    const int h1 = box[b * 4 + 1];
    const int w0 = box[b * 4 + 2];
    const int w1 = box[b * 4 + 3];
    const float cropH = (float)(h1 - h0);
    const float cropW = (float)(w1 - w0);

    // _crop_coords: src = (i+0.5)*(crop/out) - 0.5, clip [0, crop-1], floor, min(i0+1, crop-1)
    float sy = (y + 0.5f) * (cropH / (float)IMG_H) - 0.5f;
    sy = fminf(fmaxf(sy, 0.0f), cropH - 1.0f);
    const float fy0 = floorf(sy);
    const float fy1 = fminf(fy0 + 1.0f, cropH - 1.0f);
    const float wr = sy - fy0;
    const int r0 = h0 + (int)fy0;
    const int r1 = h0 + (int)fy1;

    float sx = (x + 0.5f) * (cropW / (float)IMG_W) - 0.5f;
    sx = fminf(fmaxf(sx, 0.0f), cropW - 1.0f);
    const float fx0 = floorf(sx);
    const float fx1 = fminf(fx0 + 1.0f, cropW - 1.0f);
    const float wc = sx - fx0;
    const int c0 = w0 + (int)fx0;
    const int c1 = w0 + (int)fx1;

    const float* img = images + ((size_t)b * NCH + c) * (IMG_H * IMG_W);
    const float v00 = img[r0 * IMG_W + c0];
    const float v10 = img[r1 * IMG_W + c0];
    const float v01 = img[r0 * IMG_W + c1];
    const float v11 = img[r1 * IMG_W + c1];
    const float rb0 = v00 * (1.0f - wr) + v10 * wr;
    const float rb1 = v01 * (1.0f - wr) + v11 * wr;
    const float patch = rb0 * (1.0f - wc) + rb1 * wc;

    out[((size_t)b * NCH + c) * (IMG_H * IMG_W) + p] = img[p] * 0.6f + patch * 0.4f;
}

extern "C" void kernel_launch(void* const* d_in, const int* in_sizes, int n_in,
                              void* d_out, int out_size, void* d_ws, size_t ws_size,
                              hipStream_t stream) {
    const float* images = (const float*)d_in[0];
    const float* atten  = (const float*)d_in[1];
    float* out = (float*)d_out;
    int* box = (int*)d_ws;  // 32 * 4 ints

    bbox_kernel<<<NB, 256, 0, stream>>>(atten, box);

    dim3 grid((IMG_H * IMG_W + 255) / 256, NCH, NB);
    blend_kernel<<<grid, 256, 0, stream>>>(images, box, out);
}

// Round 2
// 228.585 us; speedup vs baseline: 1.2438x; 1.2438x over previous
//
#include <hip/hip_runtime.h>

#define IMG_H 480
#define IMG_W 480
#define ATT_H 30
#define ATT_W 30
#define PAD 48
#define NCH 3
#define NB 32
#define STRIPS 16           // 480 rows / 30 rows per strip
#define ROWS_PER_STRIP 30

// Kernel A: per-sample theta = 0.5*max(atten); init raw bbox sentinels.
__global__ void __launch_bounds__(256) theta_kernel(const float* __restrict__ atten,
                                                    float* __restrict__ theta_arr,
                                                    int* __restrict__ box_raw) {
    const int b = blockIdx.x;
    const int tid = threadIdx.x;
    __shared__ float s_red[4];

    const float* a = atten + (size_t)b * ATT_H * ATT_W;
    float m = -1e30f;
    for (int i = tid; i < ATT_H * ATT_W; i += 256) m = fmaxf(m, a[i]);
    #pragma unroll
    for (int off = 32; off > 0; off >>= 1) m = fmaxf(m, __shfl_down(m, off, 64));
    if ((tid & 63) == 0) s_red[tid >> 6] = m;
    __syncthreads();
    if (tid == 0) {
        float t = fmaxf(fmaxf(s_red[0], s_red[1]), fmaxf(s_red[2], s_red[3]));
        theta_arr[b] = 0.5f * t;
        box_raw[b * 4 + 0] = IMG_H;   // min row sentinel
        box_raw[b * 4 + 1] = -1;      // max row sentinel
        box_raw[b * 4 + 2] = IMG_W;   // min col sentinel
        box_raw[b * 4 + 3] = -1;      // max col sentinel
    }
}

// Kernel B: evaluate the upsampled mask over one 30-row strip; merge bbox globally.
__global__ void __launch_bounds__(256) mask_kernel(const float* __restrict__ atten,
                                                   const float* __restrict__ theta_arr,
                                                   int* __restrict__ box_raw) {
    const int strip = blockIdx.x;
    const int b = blockIdx.y;
    const int tid = threadIdx.x;
    __shared__ float s_att[ATT_H * ATT_W];
    __shared__ int s_minr, s_maxr, s_minc, s_maxc;

    const float* a = atten + (size_t)b * ATT_H * ATT_W;
    for (int i = tid; i < ATT_H * ATT_W; i += 256) s_att[i] = a[i];
    if (tid == 0) { s_minr = IMG_H; s_maxr = -1; s_minc = IMG_W; s_maxc = -1; }
    __syncthreads();
    const float theta = theta_arr[b];

    const int y_base = strip * ROWS_PER_STRIP;
    int minr = IMG_H, maxr = -1, minc = IMG_W, maxc = -1;
    for (int p = tid; p < ROWS_PER_STRIP * IMG_W; p += 256) {
        const int yy = p / IMG_W;
        const int y = y_base + yy;
        const int x = p - yy * IMG_W;
        // source coords: (i+0.5)*(30/480) - 0.5, clipped — scale is exactly 1/16
        float sy = (y + 0.5f) * 0.0625f - 0.5f;
        sy = fminf(fmaxf(sy, 0.0f), (float)(ATT_H - 1));
        const float fy0 = floorf(sy);
        const int r0 = (int)fy0;
        const int r1 = min(r0 + 1, ATT_H - 1);
        const float wr = sy - fy0;

        float sx = (x + 0.5f) * 0.0625f - 0.5f;
        sx = fminf(fmaxf(sx, 0.0f), (float)(ATT_W - 1));
        const float fx0 = floorf(sx);
        const int c0 = (int)fx0;
        const int c1 = min(c0 + 1, ATT_W - 1);
        const float wc = sx - fx0;

        // same op order as reference: row blend first, then column blend
        const float rb0 = s_att[r0 * ATT_W + c0] * (1.0f - wr) + s_att[r1 * ATT_W + c0] * wr;
        const float rb1 = s_att[r0 * ATT_W + c1] * (1.0f - wr) + s_att[r1 * ATT_W + c1] * wr;
        const float v = rb0 * (1.0f - wc) + rb1 * wc;
        if (v >= theta) {
            minr = min(minr, y); maxr = max(maxr, y);
            minc = min(minc, x); maxc = max(maxc, x);
        }
    }
    atomicMin(&s_minr, minr); atomicMax(&s_maxr, maxr);
    atomicMin(&s_minc, minc); atomicMax(&s_maxc, maxc);
    __syncthreads();
    if (tid == 0) {
        atomicMin(&box_raw[b * 4 + 0], s_minr);
        atomicMax(&box_raw[b * 4 + 1], s_maxr);
        atomicMin(&box_raw[b * 4 + 2], s_minc);
        atomicMax(&box_raw[b * 4 + 3], s_maxc);
    }
}

// Kernel C: per-pixel crop-resize gather + mixup blend, 4 pixels (float4) per thread.
__global__ void __launch_bounds__(256) blend_kernel(const float* __restrict__ images,
                                                    const int* __restrict__ box_raw,
                                                    float* __restrict__ out) {
    const int b = blockIdx.z;
    const int c = blockIdx.y;
    const int q = blockIdx.x * 256 + threadIdx.x;   // float4 index; 480*480/4 = 57600 exact
    const int p = q * 4;
    const int y = p / IMG_W;
    const int x0 = p - y * IMG_W;                    // x0..x0+3 stay in one row (480 % 4 == 0)

    const int h0 = max(box_raw[b * 4 + 0] - PAD, 0);
    const int h1 = min(box_raw[b * 4 + 1] + PAD, IMG_H);
    const int w0 = max(box_raw[b * 4 + 2] - PAD, 0);
    const int w1 = min(box_raw[b * 4 + 3] + PAD, IMG_W);
    const float cropH = (float)(h1 - h0);
    const float cropW = (float)(w1 - w0);

    // row coords shared by all 4 pixels
    float sy = (y + 0.5f) * (cropH / (float)IMG_H) - 0.5f;
    sy = fminf(fmaxf(sy, 0.0f), cropH - 1.0f);
    const float fy0 = floorf(sy);
    const float fy1 = fminf(fy0 + 1.0f, cropH - 1.0f);
    const float wr = sy - fy0;
    const int r0 = h0 + (int)fy0;
    const int r1 = h0 + (int)fy1;

    const float* img = images + ((size_t)b * NCH + c) * (IMG_H * IMG_W);
    const float4 base = *(const float4*)(img + p);
    float4 res;

    const float invW = cropW / (float)IMG_W;
    #pragma unroll
    for (int j = 0; j < 4; ++j) {
        const int x = x0 + j;
        float sx = (x + 0.5f) * invW - 0.5f;
        sx = fminf(fmaxf(sx, 0.0f), cropW - 1.0f);
        const float fx0 = floorf(sx);
        const float fx1 = fminf(fx0 + 1.0f, cropW - 1.0f);
        const float wc = sx - fx0;
        const int c0 = w0 + (int)fx0;
        const int c1 = w0 + (int)fx1;

        const float v00 = img[r0 * IMG_W + c0];
        const float v10 = img[r1 * IMG_W + c0];
        const float v01 = img[r0 * IMG_W + c1];
        const float v11 = img[r1 * IMG_W + c1];
        const float rb0 = v00 * (1.0f - wr) + v10 * wr;
        const float rb1 = v01 * (1.0f - wr) + v11 * wr;
        const float patch = rb0 * (1.0f - wc) + rb1 * wc;
        (&res.x)[j] = (&base.x)[j] * 0.6f + patch * 0.4f;
    }

    *(float4*)(out + ((size_t)b * NCH + c) * (IMG_H * IMG_W) + p) = res;
}

extern "C" void kernel_launch(void* const* d_in, const int* in_sizes, int n_in,
                              void* d_out, int out_size, void* d_ws, size_t ws_size,
                              hipStream_t stream) {
    const float* images = (const float*)d_in[0];
    const float* atten  = (const float*)d_in[1];
    float* out = (float*)d_out;
    int* box_raw = (int*)d_ws;                       // 32*4 ints
    float* theta_arr = (float*)(box_raw + NB * 4);   // 32 floats

    theta_kernel<<<NB, 256, 0, stream>>>(atten, theta_arr, box_raw);

    dim3 mgrid(STRIPS, NB);
    mask_kernel<<<mgrid, 256, 0, stream>>>(atten, theta_arr, box_raw);

    dim3 bgrid(IMG_H * IMG_W / 4 / 256, NCH, NB);    // 225 x 3 x 32
    blend_kernel<<<bgrid, 256, 0, stream>>>(images, box_raw, out);
}

// Round 3
// 179.913 us; speedup vs baseline: 1.5803x; 1.2705x over previous
//
#include <hip/hip_runtime.h>

#define IMG_H 480
#define IMG_W 480
#define ATT_H 30
#define ATT_W 30
#define ATT_N (ATT_H * ATT_W)
#define PAD 48
#define NCH 3
#define NB 32
#define STRIPS 16           // 480 rows / 30 rows per strip
#define ROWS_PER_STRIP 30

// Kernel 1: per-strip mask bbox. Each block computes theta (0.5*max) itself
// (deterministic, identical across blocks) and writes its strip's raw bbox to
// a private slot — no global atomics, no init dependency on ws contents.
__global__ void __launch_bounds__(256) mask_kernel(const float* __restrict__ atten,
                                                   int* __restrict__ strip_box) {
    const int strip = blockIdx.x;
    const int b = blockIdx.y;
    const int tid = threadIdx.x;
    __shared__ float s_att[ATT_N];
    __shared__ float s_red[4];
    __shared__ int s_box[4];   // minr, maxr, minc, maxc

    const float* a = atten + (size_t)b * ATT_N;
    for (int i = tid; i < ATT_N; i += 256) s_att[i] = a[i];
    if (tid == 0) { s_box[0] = IMG_H; s_box[1] = -1; s_box[2] = IMG_W; s_box[3] = -1; }
    __syncthreads();

    // block max over the 900 attention values (order-independent => exact)
    float m = -1e30f;
    for (int i = tid; i < ATT_N; i += 256) m = fmaxf(m, s_att[i]);
    #pragma unroll
    for (int off = 32; off > 0; off >>= 1) m = fmaxf(m, __shfl_down(m, off, 64));
    if ((tid & 63) == 0) s_red[tid >> 6] = m;
    __syncthreads();
    const float theta = 0.5f * fmaxf(fmaxf(s_red[0], s_red[1]), fmaxf(s_red[2], s_red[3]));

    const int y_base = strip * ROWS_PER_STRIP;
    int minr = IMG_H, maxr = -1, minc = IMG_W, maxc = -1;
    for (int p = tid; p < ROWS_PER_STRIP * IMG_W; p += 256) {
        const int yy = p / IMG_W;
        const int y = y_base + yy;
        const int x = p - yy * IMG_W;
        // source coords: (i+0.5)*(30/480) - 0.5, clipped — scale is exactly 1/16
        float sy = (y + 0.5f) * 0.0625f - 0.5f;
        sy = fminf(fmaxf(sy, 0.0f), (float)(ATT_H - 1));
        const float fy0 = floorf(sy);
        const int r0 = (int)fy0;
        const int r1 = min(r0 + 1, ATT_H - 1);
        const float wr = sy - fy0;

        float sx = (x + 0.5f) * 0.0625f - 0.5f;
        sx = fminf(fmaxf(sx, 0.0f), (float)(ATT_W - 1));
        const float fx0 = floorf(sx);
        const int c0 = (int)fx0;
        const int c1 = min(c0 + 1, ATT_W - 1);
        const float wc = sx - fx0;

        // same op order as reference: row blend first, then column blend
        const float rb0 = s_att[r0 * ATT_W + c0] * (1.0f - wr) + s_att[r1 * ATT_W + c0] * wr;
        const float rb1 = s_att[r0 * ATT_W + c1] * (1.0f - wr) + s_att[r1 * ATT_W + c1] * wr;
        const float v = rb0 * (1.0f - wc) + rb1 * wc;
        if (v >= theta) {
            minr = min(minr, y); maxr = max(maxr, y);
            minc = min(minc, x); maxc = max(maxc, x);
        }
    }
    atomicMin(&s_box[0], minr); atomicMax(&s_box[1], maxr);
    atomicMin(&s_box[2], minc); atomicMax(&s_box[3], maxc);
    __syncthreads();
    if (tid == 0) {
        int* dst = strip_box + ((size_t)b * STRIPS + strip) * 4;
        dst[0] = s_box[0]; dst[1] = s_box[1]; dst[2] = s_box[2]; dst[3] = s_box[3];
    }
}

// Kernel 2: one block per (b, c, y) output row. Reduce the 16 strip-bboxes,
// stage crop rows r0/r1 in LDS, then gather taps from LDS; float4 in/out.
__global__ void __launch_bounds__(128) blend_kernel(const float* __restrict__ images,
                                                    const int* __restrict__ strip_box,
                                                    float* __restrict__ out) {
    const int y = blockIdx.x;
    const int c = blockIdx.y;
    const int b = blockIdx.z;
    const int tid = threadIdx.x;
    __shared__ float s_r0[IMG_W];
    __shared__ float s_r1[IMG_W];

    // reduce strip bboxes (uniform, L2-hit)
    int minr = IMG_H, maxr = -1, minc = IMG_W, maxc = -1;
    const int* sb = strip_box + (size_t)b * STRIPS * 4;
    #pragma unroll
    for (int s = 0; s < STRIPS; ++s) {
        minr = min(minr, sb[s * 4 + 0]); maxr = max(maxr, sb[s * 4 + 1]);
        minc = min(minc, sb[s * 4 + 2]); maxc = max(maxc, sb[s * 4 + 3]);
    }
    const int h0 = max(minr - PAD, 0);
    const int h1 = min(maxr + PAD, IMG_H);
    const int w0 = max(minc - PAD, 0);
    const int w1 = min(maxc + PAD, IMG_W);
    const float cropH = (float)(h1 - h0);
    const float cropW = (float)(w1 - w0);

    // row coords for this output row (reference op order)
    float sy = (y + 0.5f) * (cropH / (float)IMG_H) - 0.5f;
    sy = fminf(fmaxf(sy, 0.0f), cropH - 1.0f);
    const float fy0 = floorf(sy);
    const float fy1 = fminf(fy0 + 1.0f, cropH - 1.0f);
    const float wr = sy - fy0;
    const int r0 = h0 + (int)fy0;
    const int r1 = h0 + (int)fy1;

    const float* img = images + ((size_t)b * NCH + c) * (IMG_H * IMG_W);

    // stage full source rows r0, r1 into LDS (120 float4 each)
    if (tid < IMG_W / 4) {
        ((float4*)s_r0)[tid] = ((const float4*)(img + (size_t)r0 * IMG_W))[tid];
        ((float4*)s_r1)[tid] = ((const float4*)(img + (size_t)r1 * IMG_W))[tid];
    }
    __syncthreads();

    if (tid >= IMG_W / 4) return;
    const int x0 = tid * 4;
    const float4 base = ((const float4*)(img + (size_t)y * IMG_W))[tid];
    float4 res;

    const float scaleW = cropW / (float)IMG_W;
    #pragma unroll
    for (int j = 0; j < 4; ++j) {
        const int x = x0 + j;
        float sx = (x + 0.5f) * scaleW - 0.5f;
        sx = fminf(fmaxf(sx, 0.0f), cropW - 1.0f);
        const float fx0 = floorf(sx);
        const float fx1 = fminf(fx0 + 1.0f, cropW - 1.0f);
        const float wc = sx - fx0;
        const int c0 = w0 + (int)fx0;
        const int c1 = w0 + (int)fx1;

        const float v00 = s_r0[c0];
        const float v10 = s_r1[c0];
        const float v01 = s_r0[c1];
        const float v11 = s_r1[c1];
        const float rb0 = v00 * (1.0f - wr) + v10 * wr;
        const float rb1 = v01 * (1.0f - wr) + v11 * wr;
        const float patch = rb0 * (1.0f - wc) + rb1 * wc;
        (&res.x)[j] = (&base.x)[j] * 0.6f + patch * 0.4f;
    }

    ((float4*)(out + ((size_t)b * NCH + c) * (IMG_H * IMG_W) + (size_t)y * IMG_W))[tid] = res;
}

extern "C" void kernel_launch(void* const* d_in, const int* in_sizes, int n_in,
                              void* d_out, int out_size, void* d_ws, size_t ws_size,
                              hipStream_t stream) {
    const float* images = (const float*)d_in[0];
    const float* atten  = (const float*)d_in[1];
    float* out = (float*)d_out;
    int* strip_box = (int*)d_ws;   // 32 * 16 * 4 ints

    dim3 mgrid(STRIPS, NB);
    mask_kernel<<<mgrid, 256, 0, stream>>>(atten, strip_box);

    dim3 bgrid(IMG_H, NCH, NB);
    blend_kernel<<<bgrid, 128, 0, stream>>>(images, strip_box, out);
}